// Round 1
// baseline (232.858 us; speedup 1.0000x reference)
//
#include <hip/hip_runtime.h>
#include <math.h>

#define BATCH 8192
#define NTABLES 26
#define NROWS 100000
#define EMB 64

// ---------------- bottom layer 1: (8192x13) @ (512x13)^T + b, relu ----------
__global__ void mlp13_kernel(const float* __restrict__ A, const float* __restrict__ W,
                             const float* __restrict__ bias, float* __restrict__ C) {
    int idx = blockIdx.x * blockDim.x + threadIdx.x;   // over 8192*512
    int n = idx & 511;
    int m = idx >> 9;
    float s = bias[n];
#pragma unroll
    for (int k = 0; k < 13; ++k) s += A[m * 13 + k] * W[n * 13 + k];
    C[idx] = fmaxf(s, 0.f);
}

// ---------------- generic tiled GEMM: C = act(A(MxK) @ W(NxK)^T + bias) -----
// 64x64 tile, 256 threads, each thread 4x4. K ragged allowed (zero-padded).
template <int ACT>  // 1 = relu, 0 = none
__global__ void gemm_nt_kernel(const float* __restrict__ A, const float* __restrict__ W,
                               const float* __restrict__ bias, float* __restrict__ C,
                               int M, int N, int K) {
    __shared__ float As[16][68];
    __shared__ float Bs[16][68];
    const int tid = threadIdx.x;         // 0..255
    const int tx = tid & 15;             // 0..15
    const int ty = tid >> 4;             // 0..15
    const int m0 = blockIdx.x * 64;
    const int n0 = blockIdx.y * 64;

    float acc[4][4] = {};

    for (int k0 = 0; k0 < K; k0 += 16) {
#pragma unroll
        for (int i = 0; i < 4; ++i) {
            int e = tid + i * 256;       // 0..1023
            int kk = e & 15;
            int rr = e >> 4;             // 0..63
            int k = k0 + kk;
            float va = 0.f, vb = 0.f;
            if (k < K) {
                va = A[(long)(m0 + rr) * K + k];
                vb = W[(long)(n0 + rr) * K + k];
            }
            As[kk][rr] = va;
            Bs[kk][rr] = vb;
        }
        __syncthreads();
#pragma unroll
        for (int kk = 0; kk < 16; ++kk) {
            float4 a4 = *(const float4*)&As[kk][ty * 4];
            float4 b4 = *(const float4*)&Bs[kk][tx * 4];
            float av[4] = {a4.x, a4.y, a4.z, a4.w};
            float bv[4] = {b4.x, b4.y, b4.z, b4.w};
#pragma unroll
            for (int i = 0; i < 4; ++i)
#pragma unroll
                for (int j = 0; j < 4; ++j) acc[i][j] += av[i] * bv[j];
        }
        __syncthreads();
    }

#pragma unroll
    for (int i = 0; i < 4; ++i) {
        int m = m0 + ty * 4 + i;
#pragma unroll
        for (int j = 0; j < 4; ++j) {
            int n = n0 + tx * 4 + j;
            float v = acc[i][j] + bias[n];
            if (ACT == 1) v = fmaxf(v, 0.f);
            C[(long)m * N + n] = v;
        }
    }
}

// ---------------- fused embedding-bag gather + pairwise interaction ----------
// One block per sample. Builds T (27x64) in LDS: row0 = x3[b], rows 1..26 =
// emb_W[t][i0] + emb_W[t][i1]. Then R[b] = [x3(64) | lower-tri dots(351)].
__global__ void interact_kernel(const float* __restrict__ x3, const float* __restrict__ emb,
                                const int* __restrict__ lSi, float* __restrict__ R) {
    __shared__ float T[27 * 65];   // stride 65 to dodge bank conflicts
    const int b = blockIdx.x;
    const int tid = threadIdx.x;   // 384 threads

    if (tid < 64) T[tid] = x3[(long)b * 64 + tid];   // row 0 (stride-65 base 0)

    for (int e = tid; e < NTABLES * 64; e += 384) {
        int t = e >> 6;
        int d = e & 63;
        int i0 = lSi[(long)t * (BATCH * 2) + 2 * b];
        int i1 = lSi[(long)t * (BATCH * 2) + 2 * b + 1];
        const float* base = emb + (long)t * NROWS * 64;
        T[(t + 1) * 65 + d] = base[(long)i0 * 64 + d] + base[(long)i1 * 64 + d];
    }
    __syncthreads();

    float* Rb = R + (long)b * 415;
    if (tid < 64) Rb[tid] = T[tid];

    if (tid < 351) {
        // map tid -> (i, j) in tril_indices(27, k=-1) row-major order
        int p = tid;
        int i = 1;
        while (p >= i) { p -= i; ++i; }
        int j = p;
        float s = 0.f;
#pragma unroll
        for (int k = 0; k < 64; ++k) s += T[i * 65 + k] * T[j * 65 + k];
        Rb[64 + tid] = s;
    }
}

// ---------------- top layer 3: (8192x256) @ (1x256)^T + b, sigmoid ----------
// One wave per sample, shuffle reduction.
__global__ void top_final_kernel(const float* __restrict__ Z, const float* __restrict__ W,
                                 const float* __restrict__ bias, float* __restrict__ out) {
    int gtid = blockIdx.x * blockDim.x + threadIdx.x;
    int m = gtid >> 6;
    int lane = threadIdx.x & 63;
    const float* z = Z + (long)m * 256;
    float s = 0.f;
#pragma unroll
    for (int k = lane; k < 256; k += 64) s += z[k] * W[k];
#pragma unroll
    for (int off = 32; off; off >>= 1) s += __shfl_down(s, off);
    if (lane == 0) out[m] = 1.f / (1.f + expf(-(s + bias[0])));
}

extern "C" void kernel_launch(void* const* d_in, const int* in_sizes, int n_in,
                              void* d_out, int out_size, void* d_ws, size_t ws_size,
                              hipStream_t stream) {
    const float* dense = (const float*)d_in[0];
    const int*   lSi   = (const int*)d_in[1];
    // d_in[2] = lS_o (unused)
    const float* emb   = (const float*)d_in[3];
    const float* bW1 = (const float*)d_in[4];
    const float* bb1 = (const float*)d_in[5];
    const float* bW2 = (const float*)d_in[6];
    const float* bb2 = (const float*)d_in[7];
    const float* bW3 = (const float*)d_in[8];
    const float* bb3 = (const float*)d_in[9];
    const float* tW1 = (const float*)d_in[10];
    const float* tb1 = (const float*)d_in[11];
    const float* tW2 = (const float*)d_in[12];
    const float* tb2 = (const float*)d_in[13];
    const float* tW3 = (const float*)d_in[14];
    const float* tb3 = (const float*)d_in[15];
    float* out = (float*)d_out;

    float* ws = (float*)d_ws;
    float* x1 = ws;                          // 8192*512
    float* x2 = x1 + (long)BATCH * 512;      // 8192*256
    float* x3 = x2 + (long)BATCH * 256;      // 8192*64
    float* R  = x3 + (long)BATCH * 64;       // 8192*415
    float* z1 = x1;                          // alias: x1 dead after bot2
    float* z2 = x2;                          // alias: x2 dead after bot3

    // bottom MLP
    mlp13_kernel<<<(BATCH * 512) / 256, 256, 0, stream>>>(dense, bW1, bb1, x1);
    gemm_nt_kernel<1><<<dim3(BATCH / 64, 256 / 64), 256, 0, stream>>>(x1, bW2, bb2, x2, BATCH, 256, 512);
    gemm_nt_kernel<1><<<dim3(BATCH / 64, 64 / 64), 256, 0, stream>>>(x2, bW3, bb3, x3, BATCH, 64, 256);

    // fused embedding bag + interaction -> R (8192 x 415)
    interact_kernel<<<BATCH, 384, 0, stream>>>(x3, emb, lSi, R);

    // top MLP
    gemm_nt_kernel<1><<<dim3(BATCH / 64, 512 / 64), 256, 0, stream>>>(R, tW1, tb1, z1, BATCH, 512, 415);
    gemm_nt_kernel<1><<<dim3(BATCH / 64, 256 / 64), 256, 0, stream>>>(z1, tW2, tb2, z2, BATCH, 256, 512);
    top_final_kernel<<<(BATCH * 64) / 256, 256, 0, stream>>>(z2, tW3, tb3, out);
}

// Round 2
// 115.437 us; speedup vs baseline: 2.0172x; 2.0172x over previous
//
#include <hip/hip_runtime.h>
#include <hip/hip_fp16.h>
#include <math.h>

#define BATCH 8192
#define NTABLES 26
#define NROWS 100000

typedef _Float16 half8 __attribute__((ext_vector_type(8)));
typedef float floatx4 __attribute__((ext_vector_type(4)));

// ---------------- convert all weights to f16 (tW1 padded 415->416) ----------
__global__ void cvt_weights_kernel(const float* __restrict__ bW2, const float* __restrict__ bW3,
                                   const float* __restrict__ tW1, const float* __restrict__ tW2,
                                   _Float16* __restrict__ bW2h, _Float16* __restrict__ bW3h,
                                   _Float16* __restrict__ tW1h, _Float16* __restrict__ tW2h) {
    int idx = blockIdx.x * blockDim.x + threadIdx.x;
    int stride = gridDim.x * blockDim.x;
    for (int i = idx; i < 256 * 512; i += stride) bW2h[i] = (_Float16)bW2[i];
    for (int i = idx; i < 64 * 256; i += stride) bW3h[i] = (_Float16)bW3[i];
    for (int i = idx; i < 256 * 512; i += stride) tW2h[i] = (_Float16)tW2[i];
    for (int i = idx; i < 512 * 416; i += stride) {
        int r = i / 416, c = i - r * 416;
        tW1h[i] = (c < 415) ? (_Float16)tW1[r * 415 + c] : (_Float16)0.f;
    }
}

// ---------------- bottom layer 1: (8192x13) @ (512x13)^T + b, relu ----------
__global__ void mlp13_kernel(const float* __restrict__ A, const float* __restrict__ W,
                             const float* __restrict__ bias, _Float16* __restrict__ C) {
    int idx = blockIdx.x * blockDim.x + threadIdx.x;   // over 8192*512
    int n = idx & 511;
    int m = idx >> 9;
    float s = bias[n];
#pragma unroll
    for (int k = 0; k < 13; ++k) s += A[m * 13 + k] * W[n * 13 + k];
    C[idx] = (_Float16)fmaxf(s, 0.f);
}

// ---------------- MFMA f16 GEMM: C = relu(A(MxK) @ W(NxK)^T + bias) ---------
// 64x64 tile, 256 threads = 4 waves (2x2), wave tile 32x32 = 2x2 frags of
// 16x16x32. A/W row-major f16, K % 32 == 0. Output f16.
template <int ACT>
__global__ __launch_bounds__(256) void gemm16_kernel(
    const _Float16* __restrict__ A, const _Float16* __restrict__ W,
    const float* __restrict__ bias, _Float16* __restrict__ C,
    int M, int N, int K) {
    __shared__ _Float16 As[64 * 40];   // row stride 40 halves (pad)
    __shared__ _Float16 Ws[64 * 40];
    const int tid = threadIdx.x;
    const int lane = tid & 63;
    const int wave = tid >> 6;       // 0..3
    const int wm = wave >> 1;        // 0..1
    const int wn = wave & 1;         // 0..1
    const int m0 = blockIdx.x * 64;
    const int n0 = blockIdx.y * 64;

    const int srow = tid >> 2;           // 0..63
    const int scol = (tid & 3) * 8;      // 0,8,16,24

    const int g = lane >> 4;             // 0..3
    const int r = lane & 15;             // 0..15

    floatx4 acc[2][2] = {};

    const _Float16* Ap = &A[(long)(m0 + srow) * K + scol];
    const _Float16* Wp = &W[(long)(n0 + srow) * K + scol];

    for (int k0 = 0; k0 < K; k0 += 32) {
        int4 va = *(const int4*)&Ap[k0];
        int4 vb = *(const int4*)&Wp[k0];
        __syncthreads();
        *(int4*)&As[srow * 40 + scol] = va;
        *(int4*)&Ws[srow * 40 + scol] = vb;
        __syncthreads();
        half8 a0 = *(const half8*)&As[(wm * 32 + r) * 40 + g * 8];
        half8 a1 = *(const half8*)&As[(wm * 32 + 16 + r) * 40 + g * 8];
        half8 b0 = *(const half8*)&Ws[(wn * 32 + r) * 40 + g * 8];
        half8 b1 = *(const half8*)&Ws[(wn * 32 + 16 + r) * 40 + g * 8];
        acc[0][0] = __builtin_amdgcn_mfma_f32_16x16x32_f16(a0, b0, acc[0][0], 0, 0, 0);
        acc[0][1] = __builtin_amdgcn_mfma_f32_16x16x32_f16(a0, b1, acc[0][1], 0, 0, 0);
        acc[1][0] = __builtin_amdgcn_mfma_f32_16x16x32_f16(a1, b0, acc[1][0], 0, 0, 0);
        acc[1][1] = __builtin_amdgcn_mfma_f32_16x16x32_f16(a1, b1, acc[1][1], 0, 0, 0);
    }

#pragma unroll
    for (int fi = 0; fi < 2; ++fi) {
#pragma unroll
        for (int fj = 0; fj < 2; ++fj) {
            int row0 = m0 + wm * 32 + fi * 16 + g * 4;
            int col = n0 + wn * 32 + fj * 16 + r;
            float bv = bias[col];
#pragma unroll
            for (int q = 0; q < 4; ++q) {
                float v = acc[fi][fj][q] + bv;
                if (ACT) v = fmaxf(v, 0.f);
                C[(long)(row0 + q) * N + col] = (_Float16)v;
            }
        }
    }
}

// ---------------- fused embedding-bag gather + pairwise interaction ----------
// One block per sample. T (27x64) in LDS (f32). R row stride 416, col 415 = 0.
__global__ void interact_kernel(const _Float16* __restrict__ x3, const float* __restrict__ emb,
                                const int* __restrict__ lSi, _Float16* __restrict__ R) {
    __shared__ float T[27 * 65];
    const int b = blockIdx.x;
    const int tid = threadIdx.x;   // 384 threads

    if (tid < 64) T[tid] = (float)x3[(long)b * 64 + tid];

    for (int e = tid; e < NTABLES * 64; e += 384) {
        int t = e >> 6;
        int d = e & 63;
        int i0 = lSi[(long)t * (BATCH * 2) + 2 * b];
        int i1 = lSi[(long)t * (BATCH * 2) + 2 * b + 1];
        const float* base = emb + (long)t * NROWS * 64;
        T[(t + 1) * 65 + d] = base[(long)i0 * 64 + d] + base[(long)i1 * 64 + d];
    }
    __syncthreads();

    _Float16* Rb = R + (long)b * 416;
    if (tid < 64) Rb[tid] = (_Float16)T[tid];
    if (tid == 380) Rb[415] = (_Float16)0.f;

    if (tid < 351) {
        int p = tid;
        int i = 1;
        while (p >= i) { p -= i; ++i; }
        int j = p;
        float s = 0.f;
#pragma unroll
        for (int k = 0; k < 64; ++k) s += T[i * 65 + k] * T[j * 65 + k];
        Rb[64 + tid] = (_Float16)s;
    }
}

// ---------------- top layer 3: (8192x256) @ (1x256)^T + b, sigmoid ----------
__global__ void top_final_kernel(const _Float16* __restrict__ Z, const float* __restrict__ W,
                                 const float* __restrict__ bias, float* __restrict__ out) {
    int gtid = blockIdx.x * blockDim.x + threadIdx.x;
    int m = gtid >> 6;
    int lane = threadIdx.x & 63;
    const _Float16* z = Z + (long)m * 256;
    float s = 0.f;
#pragma unroll
    for (int k = lane; k < 256; k += 64) s += (float)z[k] * W[k];
#pragma unroll
    for (int off = 32; off; off >>= 1) s += __shfl_down(s, off);
    if (lane == 0) out[m] = 1.f / (1.f + expf(-(s + bias[0])));
}

extern "C" void kernel_launch(void* const* d_in, const int* in_sizes, int n_in,
                              void* d_out, int out_size, void* d_ws, size_t ws_size,
                              hipStream_t stream) {
    const float* dense = (const float*)d_in[0];
    const int*   lSi   = (const int*)d_in[1];
    const float* emb   = (const float*)d_in[3];
    const float* bW1 = (const float*)d_in[4];
    const float* bb1 = (const float*)d_in[5];
    const float* bW2 = (const float*)d_in[6];
    const float* bb2 = (const float*)d_in[7];
    const float* bW3 = (const float*)d_in[8];
    const float* bb3 = (const float*)d_in[9];
    const float* tW1 = (const float*)d_in[10];
    const float* tb1 = (const float*)d_in[11];
    const float* tW2 = (const float*)d_in[12];
    const float* tb2 = (const float*)d_in[13];
    const float* tW3 = (const float*)d_in[14];
    const float* tb3 = (const float*)d_in[15];
    float* out = (float*)d_out;

    char* ws = (char*)d_ws;
    _Float16* x1h = (_Float16*)ws;                                   // 8192*512
    _Float16* x2h = (_Float16*)(ws + 8388608);                       // 8192*256
    _Float16* x3h = (_Float16*)(ws + 8388608 + 4194304);             // 8192*64
    _Float16* Rh  = (_Float16*)(ws + 8388608 + 4194304 + 1048576);   // 8192*416
    char* wbase = ws + 8388608 + 4194304 + 1048576 + 6815744;
    _Float16* bW2h = (_Float16*)wbase;                   // 256*512
    _Float16* bW3h = (_Float16*)(wbase + 262144);        // 64*256
    _Float16* tW1h = (_Float16*)(wbase + 262144 + 32768);            // 512*416
    _Float16* tW2h = (_Float16*)(wbase + 262144 + 32768 + 425984);   // 256*512
    _Float16* z1h = x1h;   // x1h dead after bot2
    _Float16* z2h = x2h;   // x2h dead after bot3

    cvt_weights_kernel<<<512, 256, 0, stream>>>(bW2, bW3, tW1, tW2, bW2h, bW3h, tW1h, tW2h);

    // bottom MLP
    mlp13_kernel<<<(BATCH * 512) / 256, 256, 0, stream>>>(dense, bW1, bb1, x1h);
    gemm16_kernel<1><<<dim3(BATCH / 64, 256 / 64), 256, 0, stream>>>(x1h, bW2h, bb2, x2h, BATCH, 256, 512);
    gemm16_kernel<1><<<dim3(BATCH / 64, 64 / 64), 256, 0, stream>>>(x2h, bW3h, bb3, x3h, BATCH, 64, 256);

    // fused embedding bag + interaction -> Rh (8192 x 416, col 415 zero)
    interact_kernel<<<BATCH, 384, 0, stream>>>(x3h, emb, lSi, Rh);

    // top MLP
    gemm16_kernel<1><<<dim3(BATCH / 64, 512 / 64), 256, 0, stream>>>(Rh, tW1h, tb1, z1h, BATCH, 512, 416);
    gemm16_kernel<1><<<dim3(BATCH / 64, 256 / 64), 256, 0, stream>>>(z1h, tW2h, tb2, z2h, BATCH, 256, 512);
    top_final_kernel<<<(BATCH * 64) / 256, 256, 0, stream>>>(z2h, tW3, tb3, out);
}

// Round 3
// 101.266 us; speedup vs baseline: 2.2995x; 1.1399x over previous
//
#include <hip/hip_runtime.h>
#include <hip/hip_fp16.h>
#include <math.h>

#define BATCH 8192
#define NTABLES 26
#define NROWS 100000

typedef _Float16 half8 __attribute__((ext_vector_type(8)));
typedef float floatx4 __attribute__((ext_vector_type(4)));

#define ASYNC_COPY16(gptr, lptr)                                                  \
    __builtin_amdgcn_global_load_lds(                                             \
        (const __attribute__((address_space(1))) void*)(gptr),                    \
        (__attribute__((address_space(3))) void*)(lptr), 16, 0, 0)

// ---------------- convert all weights to f16 (tW1 padded 415->416) ----------
__global__ void cvt_weights_kernel(const float* __restrict__ bW2, const float* __restrict__ bW3,
                                   const float* __restrict__ tW1, const float* __restrict__ tW2,
                                   _Float16* __restrict__ bW2h, _Float16* __restrict__ bW3h,
                                   _Float16* __restrict__ tW1h, _Float16* __restrict__ tW2h) {
    int idx = blockIdx.x * blockDim.x + threadIdx.x;
    int stride = gridDim.x * blockDim.x;
    for (int i = idx; i < 256 * 512; i += stride) bW2h[i] = (_Float16)bW2[i];
    for (int i = idx; i < 64 * 256; i += stride) bW3h[i] = (_Float16)bW3[i];
    for (int i = idx; i < 256 * 512; i += stride) tW2h[i] = (_Float16)tW2[i];
    for (int i = idx; i < 512 * 416; i += stride) {
        int r = i / 416, c = i - r * 416;
        tW1h[i] = (c < 415) ? (_Float16)tW1[r * 415 + c] : (_Float16)0.f;
    }
}

// ---------------- bottom layer 1: (8192x13) @ (512x13)^T + b, relu ----------
__global__ void mlp13_kernel(const float* __restrict__ A, const float* __restrict__ W,
                             const float* __restrict__ bias, _Float16* __restrict__ C) {
    int idx = blockIdx.x * blockDim.x + threadIdx.x;   // over 8192*512
    int n = idx & 511;
    int m = idx >> 9;
    float s = bias[n];
#pragma unroll
    for (int k = 0; k < 13; ++k) s += A[m * 13 + k] * W[n * 13 + k];
    C[idx] = (_Float16)fmaxf(s, 0.f);
}

// ------- m97-style MFMA GEMM: C = relu(A(MxK) @ W(NxK)^T + bias), f16 -------
// 128x128 tile, BK=32, 256 threads = 4 waves (2x2), wave tile 64x64 = 4x4
// frags of 16x16x32. global_load_lds width-16 staging into linear LDS.
// Requires M%128==0, N%128==0, K%32==0, 16B-aligned rows.
template <int ACT>
__global__ __launch_bounds__(256) void gemm_mfma_kernel(
    const _Float16* __restrict__ A, const _Float16* __restrict__ W,
    const float* __restrict__ bias, _Float16* __restrict__ C,
    int M, int N, int K) {
    __shared__ _Float16 As[128 * 32];
    __shared__ _Float16 Bs[128 * 32];
    const int tid = threadIdx.x;
    const int lane = tid & 63;
    const int wave = tid >> 6;       // 0..3
    const int wm = wave >> 1;        // 0..1
    const int wn = wave & 1;         // 0..1
    const int m0 = blockIdx.x * 128;
    const int n0 = blockIdx.y * 128;
    const int r15 = lane & 15;
    const int g = lane >> 4;

    floatx4 acc[4][4] = {};

    for (int k0 = 0; k0 < K; k0 += 32) {
        __syncthreads();   // prev-iter LDS reads done before overwrite
#pragma unroll
        for (int rr = 0; rr < 2; ++rr) {
            int c = rr * 256 + tid;            // 16B chunk id (512 per matrix)
            int c0 = rr * 256 + wave * 64;     // wave-uniform chunk base
            const _Float16* gA = A + (long)(m0 + (c >> 2)) * K + k0 + (c & 3) * 8;
            ASYNC_COPY16(gA, &As[c0 * 8]);
            const _Float16* gB = W + (long)(n0 + (c >> 2)) * K + k0 + (c & 3) * 8;
            ASYNC_COPY16(gB, &Bs[c0 * 8]);
        }
        __syncthreads();   // compiler drains vmcnt before barrier

        half8 a[4], b[4];
#pragma unroll
        for (int mi = 0; mi < 4; ++mi)
            a[mi] = *(const half8*)&As[(wm * 64 + mi * 16 + r15) * 32 + g * 8];
#pragma unroll
        for (int nj = 0; nj < 4; ++nj)
            b[nj] = *(const half8*)&Bs[(wn * 64 + nj * 16 + r15) * 32 + g * 8];
#pragma unroll
        for (int mi = 0; mi < 4; ++mi)
#pragma unroll
            for (int nj = 0; nj < 4; ++nj)
                acc[mi][nj] = __builtin_amdgcn_mfma_f32_16x16x32_f16(a[mi], b[nj], acc[mi][nj], 0, 0, 0);
    }

#pragma unroll
    for (int mi = 0; mi < 4; ++mi) {
#pragma unroll
        for (int nj = 0; nj < 4; ++nj) {
            int col = n0 + wn * 64 + nj * 16 + r15;
            float bv = bias[col];
            int row0 = m0 + wm * 64 + mi * 16 + g * 4;
#pragma unroll
            for (int q = 0; q < 4; ++q) {
                float v = acc[mi][nj][q] + bv;
                if (ACT) v = fmaxf(v, 0.f);
                C[(long)(row0 + q) * N + col] = (_Float16)v;
            }
        }
    }
}

// ---------------- small GEMM for bot3 (N=64): 64x64 tile, reg-staged --------
template <int ACT>
__global__ __launch_bounds__(256) void gemm16_kernel(
    const _Float16* __restrict__ A, const _Float16* __restrict__ W,
    const float* __restrict__ bias, _Float16* __restrict__ C,
    int M, int N, int K) {
    __shared__ _Float16 As[64 * 40];
    __shared__ _Float16 Ws[64 * 40];
    const int tid = threadIdx.x;
    const int lane = tid & 63;
    const int wave = tid >> 6;
    const int wm = wave >> 1;
    const int wn = wave & 1;
    const int m0 = blockIdx.x * 64;
    const int n0 = blockIdx.y * 64;
    const int srow = tid >> 2;
    const int scol = (tid & 3) * 8;
    const int g = lane >> 4;
    const int r = lane & 15;

    floatx4 acc[2][2] = {};
    const _Float16* Ap = &A[(long)(m0 + srow) * K + scol];
    const _Float16* Wp = &W[(long)(n0 + srow) * K + scol];

    for (int k0 = 0; k0 < K; k0 += 32) {
        int4 va = *(const int4*)&Ap[k0];
        int4 vb = *(const int4*)&Wp[k0];
        __syncthreads();
        *(int4*)&As[srow * 40 + scol] = va;
        *(int4*)&Ws[srow * 40 + scol] = vb;
        __syncthreads();
        half8 a0 = *(const half8*)&As[(wm * 32 + r) * 40 + g * 8];
        half8 a1 = *(const half8*)&As[(wm * 32 + 16 + r) * 40 + g * 8];
        half8 b0 = *(const half8*)&Ws[(wn * 32 + r) * 40 + g * 8];
        half8 b1 = *(const half8*)&Ws[(wn * 32 + 16 + r) * 40 + g * 8];
        acc[0][0] = __builtin_amdgcn_mfma_f32_16x16x32_f16(a0, b0, acc[0][0], 0, 0, 0);
        acc[0][1] = __builtin_amdgcn_mfma_f32_16x16x32_f16(a0, b1, acc[0][1], 0, 0, 0);
        acc[1][0] = __builtin_amdgcn_mfma_f32_16x16x32_f16(a1, b0, acc[1][0], 0, 0, 0);
        acc[1][1] = __builtin_amdgcn_mfma_f32_16x16x32_f16(a1, b1, acc[1][1], 0, 0, 0);
    }

#pragma unroll
    for (int fi = 0; fi < 2; ++fi)
#pragma unroll
        for (int fj = 0; fj < 2; ++fj) {
            int row0 = m0 + wm * 32 + fi * 16 + g * 4;
            int col = n0 + wn * 32 + fj * 16 + r;
            float bv = bias[col];
#pragma unroll
            for (int q = 0; q < 4; ++q) {
                float v = acc[fi][fj][q] + bv;
                if (ACT) v = fmaxf(v, 0.f);
                C[(long)(row0 + q) * N + col] = (_Float16)v;
            }
        }
}

// ------- fused embedding-bag gather + MFMA pairwise interaction -------------
// 4 waves/block, one sample per wave. T (32x64 f16, stride 72) per wave in
// LDS; Z = T*T^T via 6 MFMAs (symmetric); tril(Z,-1) -> R[64..414].
__global__ __launch_bounds__(256) void interact_mfma_kernel(
    const _Float16* __restrict__ x3, const float* __restrict__ emb,
    const int* __restrict__ lSi, _Float16* __restrict__ R) {
    __shared__ _Float16 T[4][32 * 72];
    const int tid = threadIdx.x;
    const int lane = tid & 63;
    const int wave = tid >> 6;
    const int s = blockIdx.x * 4 + wave;
    _Float16* Tw = T[wave];

    // row 0 = x3[s]
    Tw[lane] = x3[(long)s * 64 + lane];
    // rows 1..26 = emb bag sums (f32 gather, f16 store)
#pragma unroll 4
    for (int t = 0; t < NTABLES; ++t) {
        int i0 = lSi[(long)t * (BATCH * 2) + 2 * s];
        int i1 = lSi[(long)t * (BATCH * 2) + 2 * s + 1];
        const float* base = emb + (long)t * NROWS * 64;
        float v = base[(long)i0 * 64 + lane] + base[(long)i1 * 64 + lane];
        Tw[(t + 1) * 72 + lane] = (_Float16)v;
    }
    // wave-synchronous: no barrier needed (compiler inserts lgkmcnt waits)

    const int r15 = lane & 15;
    const int g = lane >> 4;
    half8 f[2][2];
#pragma unroll
    for (int ri = 0; ri < 2; ++ri)
#pragma unroll
        for (int ks = 0; ks < 2; ++ks)
            f[ri][ks] = *(const half8*)&Tw[(ri * 16 + r15) * 72 + ks * 32 + g * 8];

    floatx4 a00 = {}, a10 = {}, a11 = {};
#pragma unroll
    for (int ks = 0; ks < 2; ++ks) {
        a00 = __builtin_amdgcn_mfma_f32_16x16x32_f16(f[0][ks], f[0][ks], a00, 0, 0, 0);
        a10 = __builtin_amdgcn_mfma_f32_16x16x32_f16(f[1][ks], f[0][ks], a10, 0, 0, 0);
        a11 = __builtin_amdgcn_mfma_f32_16x16x32_f16(f[1][ks], f[1][ks], a11, 0, 0, 0);
    }

    _Float16* Rb = R + (long)s * 416;
    Rb[lane] = Tw[lane];              // x copy (exact f16)
    if (lane == 63) Rb[415] = (_Float16)0.f;

    const int r4 = g * 4;
#pragma unroll
    for (int q = 0; q < 4; ++q) {
        int i = r4 + q, j = r15;      // block (0,0)
        if (i > j) Rb[64 + i * (i - 1) / 2 + j] = (_Float16)a00[q];
    }
#pragma unroll
    for (int q = 0; q < 4; ++q) {
        int i = 16 + r4 + q, j = r15; // block (1,0)
        if (i <= 26) Rb[64 + i * (i - 1) / 2 + j] = (_Float16)a10[q];
    }
#pragma unroll
    for (int q = 0; q < 4; ++q) {
        int i = 16 + r4 + q, j = 16 + r15; // block (1,1)
        if (i <= 26 && i > j) Rb[64 + i * (i - 1) / 2 + j] = (_Float16)a11[q];
    }
}

// ---------------- top layer 3: (8192x256) @ (1x256)^T + b, sigmoid ----------
__global__ void top_final_kernel(const _Float16* __restrict__ Z, const float* __restrict__ W,
                                 const float* __restrict__ bias, float* __restrict__ out) {
    int gtid = blockIdx.x * blockDim.x + threadIdx.x;
    int m = gtid >> 6;
    int lane = threadIdx.x & 63;
    const _Float16* z = Z + (long)m * 256;
    float s = 0.f;
#pragma unroll
    for (int k = lane; k < 256; k += 64) s += (float)z[k] * W[k];
#pragma unroll
    for (int off = 32; off; off >>= 1) s += __shfl_down(s, off);
    if (lane == 0) out[m] = 1.f / (1.f + expf(-(s + bias[0])));
}

extern "C" void kernel_launch(void* const* d_in, const int* in_sizes, int n_in,
                              void* d_out, int out_size, void* d_ws, size_t ws_size,
                              hipStream_t stream) {
    const float* dense = (const float*)d_in[0];
    const int*   lSi   = (const int*)d_in[1];
    const float* emb   = (const float*)d_in[3];
    const float* bW1 = (const float*)d_in[4];
    const float* bb1 = (const float*)d_in[5];
    const float* bW2 = (const float*)d_in[6];
    const float* bb2 = (const float*)d_in[7];
    const float* bW3 = (const float*)d_in[8];
    const float* bb3 = (const float*)d_in[9];
    const float* tW1 = (const float*)d_in[10];
    const float* tb1 = (const float*)d_in[11];
    const float* tW2 = (const float*)d_in[12];
    const float* tb2 = (const float*)d_in[13];
    const float* tW3 = (const float*)d_in[14];
    const float* tb3 = (const float*)d_in[15];
    float* out = (float*)d_out;

    char* ws = (char*)d_ws;
    _Float16* x1h = (_Float16*)ws;                                   // 8192*512
    _Float16* x2h = (_Float16*)(ws + 8388608);                       // 8192*256
    _Float16* x3h = (_Float16*)(ws + 8388608 + 4194304);             // 8192*64
    _Float16* Rh  = (_Float16*)(ws + 8388608 + 4194304 + 1048576);   // 8192*416
    char* wbase = ws + 8388608 + 4194304 + 1048576 + 6815744;
    _Float16* bW2h = (_Float16*)wbase;                               // 256*512
    _Float16* bW3h = (_Float16*)(wbase + 262144);                    // 64*256
    _Float16* tW1h = (_Float16*)(wbase + 262144 + 32768);            // 512*416
    _Float16* tW2h = (_Float16*)(wbase + 262144 + 32768 + 425984);   // 256*512
    _Float16* z1h = x1h;
    _Float16* z2h = x2h;

    cvt_weights_kernel<<<512, 256, 0, stream>>>(bW2, bW3, tW1, tW2, bW2h, bW3h, tW1h, tW2h);

    // bottom MLP
    mlp13_kernel<<<(BATCH * 512) / 256, 256, 0, stream>>>(dense, bW1, bb1, x1h);
    gemm_mfma_kernel<1><<<dim3(BATCH / 128, 256 / 128), 256, 0, stream>>>(x1h, bW2h, bb2, x2h, BATCH, 256, 512);
    gemm16_kernel<1><<<dim3(BATCH / 64, 64 / 64), 256, 0, stream>>>(x2h, bW3h, bb3, x3h, BATCH, 64, 256);

    // fused embedding bag + MFMA interaction -> Rh (8192 x 416)
    interact_mfma_kernel<<<BATCH / 4, 256, 0, stream>>>(x3h, emb, lSi, Rh);

    // top MLP
    gemm_mfma_kernel<1><<<dim3(BATCH / 128, 512 / 128), 256, 0, stream>>>(Rh, tW1h, tb1, z1h, BATCH, 512, 416);
    gemm_mfma_kernel<1><<<dim3(BATCH / 128, 256 / 128), 256, 0, stream>>>(z1h, tW2h, tb2, z2h, BATCH, 256, 512);
    top_final_kernel<<<(BATCH * 64) / 256, 256, 0, stream>>>(z2h, tW3, tb3, out);
}